// Round 4
// baseline (570.923 us; speedup 1.0000x reference)
//
#include <hip/hip_runtime.h>
#include <math.h>

#define B_ 4
#define L_ 64
#define D_ 512
#define DI_ 1024
#define N_ 16
#define DC_ 4
#define R_ 32
#define NL_ 4
#define SD_ 17
#define AD_ 6
#define T_ 256   // 4*L
#define CH_ 8    // scan chunks
#define TC_ 32   // T_/CH_

// bf16 weight segment sizes (elements)
#define NW_IN  (NL_ * 2 * DI_ * D_)   // 4194304
#define NW_OUT (NL_ * D_ * DI_)       // 2097152
#define NW_XP  (NL_ * 64 * DI_)       // 262144
#define NW_TOT (NW_IN + NW_OUT + NW_XP)  // 6553600

typedef short bf16x8 __attribute__((ext_vector_type(8)));
typedef float f32x4 __attribute__((ext_vector_type(4)));

__device__ __forceinline__ float silu_f(float v) { return v / (1.f + __expf(-v)); }
__device__ __forceinline__ float softplus_f(float v) {
    return fmaxf(v, 0.f) + log1pf(__expf(-fabsf(v)));
}
__device__ __forceinline__ unsigned short f2bs(float f) {
    unsigned u = __float_as_uint(f);
    u += 0x7fffu + ((u >> 16) & 1u);
    return (unsigned short)(u >> 16);
}
__device__ __forceinline__ float bs2f(unsigned short s) {
    return __uint_as_float(((unsigned)s) << 16);
}

// ---------------------------------------------------------------------------
// One-time: weights fp32 -> bf16 (in_w | out_w | xp_w)
// ---------------------------------------------------------------------------
__global__ __launch_bounds__(256) void wcvt_kernel(
    const float* __restrict__ in_w, const float* __restrict__ out_w,
    const float* __restrict__ xp_w, unsigned short* __restrict__ wb)
{
    const int i = blockIdx.x * 256 + threadIdx.x;   // float4 index
    if (i >= NW_TOT / 4) return;
    const int e = i * 4;
    const float* src; int off;
    if (e < NW_IN)               { src = in_w;  off = e; }
    else if (e < NW_IN + NW_OUT) { src = out_w; off = e - NW_IN; }
    else                         { src = xp_w;  off = e - NW_IN - NW_OUT; }
    const float4 v = *(const float4*)(src + off);
    ushort4 o;
    o.x = f2bs(v.x); o.y = f2bs(v.y); o.z = f2bs(v.z); o.w = f2bs(v.w);
    *(ushort4*)(wb + e) = o;
}

// ---------------------------------------------------------------------------
// Embedding
// ---------------------------------------------------------------------------
__global__ __launch_bounds__(512) void embed_kernel(
    const float* __restrict__ states, const float* __restrict__ actions,
    const float* __restrict__ rtg, const float* __restrict__ ctg,
    const int* __restrict__ ts,
    const float* __restrict__ es_w, const float* __restrict__ es_b,
    const float* __restrict__ ea_w, const float* __restrict__ ea_b,
    const float* __restrict__ er_w, const float* __restrict__ er_b,
    const float* __restrict__ ec_w, const float* __restrict__ ec_b,
    const float* __restrict__ et_w, float* __restrict__ x)
{
    const int bl = blockIdx.x;
    const int d = threadIdx.x;
    const float te = et_w[(size_t)ts[bl] * D_ + d];
    const float r = rtg[bl] * er_w[d] + er_b[d] + te;
    const float c = ctg[bl] * ec_w[d] + ec_b[d] + te;
    float s = es_b[d] + te;
#pragma unroll
    for (int k = 0; k < SD_; ++k) s += states[bl * SD_ + k] * es_w[d * SD_ + k];
    float a = ea_b[d] + te;
#pragma unroll
    for (int k = 0; k < AD_; ++k) a += actions[bl * AD_ + k] * ea_w[d * AD_ + k];
    float* xp = x + (size_t)bl * 4 * D_;
    xp[0 * D_ + d] = r;
    xp[1 * D_ + d] = c;
    xp[2 * D_ + d] = s;
    xp[3 * D_ + d] = a;
}

// ---------------------------------------------------------------------------
// LayerNorm (+ optional residual partial sum from split-K out_proj).
// MODE 0: ln(x) -> bf16 out.  MODE 1: x += p0+p1 (stored), ln -> bf16 out.
// MODE 2: x += p0+p1, ln -> fp32 out.
// ---------------------------------------------------------------------------
template <int MODE>
__global__ __launch_bounds__(256) void ln2_kernel(
    float* __restrict__ x, const float* __restrict__ p0,
    const float* __restrict__ p1,
    const float* __restrict__ w, const float* __restrict__ b,
    void* __restrict__ o_)
{
    const int tok = blockIdx.x;
    const int tid = threadIdx.x;
    float2 v = reinterpret_cast<float2*>(x + (size_t)tok * D_)[tid];
    if (MODE >= 1) {
        const float2 a0 = reinterpret_cast<const float2*>(p0 + (size_t)tok * D_)[tid];
        const float2 a1 = reinterpret_cast<const float2*>(p1 + (size_t)tok * D_)[tid];
        v.x += a0.x + a1.x;
        v.y += a0.y + a1.y;
        reinterpret_cast<float2*>(x + (size_t)tok * D_)[tid] = v;
    }
    float s = v.x + v.y;
#pragma unroll
    for (int off = 1; off < 64; off <<= 1) s += __shfl_xor(s, off);
    __shared__ float red[8];
    const int wv = tid >> 6;
    if ((tid & 63) == 0) red[wv] = s;
    __syncthreads();
    const float mean = (red[0] + red[1] + red[2] + red[3]) * (1.f / D_);
    const float dx = v.x - mean, dy = v.y - mean;
    float q = dx * dx + dy * dy;
#pragma unroll
    for (int off = 1; off < 64; off <<= 1) q += __shfl_xor(q, off);
    if ((tid & 63) == 0) red[4 + wv] = q;
    __syncthreads();
    const float var = (red[4] + red[5] + red[6] + red[7]) * (1.f / D_);
    const float r = rsqrtf(var + 1e-5f);
    const int d0 = tid * 2;
    const float o0 = dx * r * w[d0] + b[d0];
    const float o1 = dy * r * w[d0 + 1] + b[d0 + 1];
    if (MODE == 2) {
        float* o = (float*)o_;
        o[(size_t)tok * D_ + d0] = o0;
        o[(size_t)tok * D_ + d0 + 1] = o1;
    } else {
        unsigned short* o = (unsigned short*)o_;
        o[(size_t)tok * D_ + d0] = f2bs(o0);
        o[(size_t)tok * D_ + d0 + 1] = f2bs(o1);
    }
}

// ---------------------------------------------------------------------------
// MFMA bf16 GEMM, A and W both bf16, K compile-time.
// 4 waves (2x2), wave tile 32x32 (MR=NR=2), block tile 64x64.
// EPI 3: in_proj split store (col<DI -> xmb bf16; col>=DI -> zs=silu bf16)
// EPI 4: split-K partial store to C + blockIdx.z*(1024*512), k base z*KT
// EPI 0: plain fp32 store
// ---------------------------------------------------------------------------
template <int MR, int NR, int EPI, int KT>
__global__ __launch_bounds__(256) void gemm3(
    const unsigned short* __restrict__ A, int lda,
    const unsigned short* __restrict__ W, int ldw,
    float* __restrict__ C, unsigned short* __restrict__ Cb1,
    unsigned short* __restrict__ Cb2, int N)
{
    const int lane = threadIdx.x & 63, wid = threadIdx.x >> 6;
    const int r = lane & 15, kq = lane >> 4;
    const int wm = blockIdx.y * (2 * MR * 16) + (wid >> 1) * (MR * 16);
    const int wn = blockIdx.x * (2 * NR * 16) + (wid & 1) * (NR * 16);
    const int kb = (EPI == 4) ? blockIdx.z * KT : 0;
    f32x4 acc[MR][NR] = {};
#pragma unroll 4
    for (int k0 = 0; k0 < KT; k0 += 32) {
        bf16x8 a[MR], b[NR];
#pragma unroll
        for (int i = 0; i < MR; ++i)
            a[i] = *(const bf16x8*)(A + (size_t)(wm + i * 16 + r) * lda + kb + k0 + kq * 8);
#pragma unroll
        for (int j = 0; j < NR; ++j)
            b[j] = *(const bf16x8*)(W + (size_t)(wn + j * 16 + r) * ldw + kb + k0 + kq * 8);
#pragma unroll
        for (int i = 0; i < MR; ++i)
#pragma unroll
            for (int j = 0; j < NR; ++j)
                acc[i][j] = __builtin_amdgcn_mfma_f32_16x16x32_bf16(a[i], b[j], acc[i][j], 0, 0, 0);
    }
    // C/D layout: col = lane&15, row = (lane>>4)*4 + reg
#pragma unroll
    for (int i = 0; i < MR; ++i)
#pragma unroll
        for (int j = 0; j < NR; ++j)
#pragma unroll
            for (int g = 0; g < 4; ++g) {
                const int row = wm + i * 16 + kq * 4 + g;
                const int col = wn + j * 16 + r;
                const float val = acc[i][j][g];
                if (EPI == 3) {
                    if (col < DI_) Cb1[(size_t)row * DI_ + col] = f2bs(val);
                    else Cb2[(size_t)row * DI_ + (col - DI_)] = f2bs(silu_f(val));
                } else if (EPI == 4) {
                    C[(size_t)blockIdx.z * (1024 * 512) + (size_t)row * 512 + col] = val;
                } else {
                    C[(size_t)row * N + col] = val;
                }
            }
}

// ---------------------------------------------------------------------------
// Fused conv1d+silu + xp GEMM.
// Block handles 16 token-rows: Phase A computes conv+silu over 16x1024 into
// XOR-swizzled LDS (and stores xcb to global for the scan); Phase B does the
// 4-way split-K xp GEMM (16 x 64 x 1024) from LDS, reduce, write dbc fp32.
// ---------------------------------------------------------------------------
__global__ __launch_bounds__(256) void convxp_kernel(
    const unsigned short* __restrict__ xmb, const float* __restrict__ cw,
    const float* __restrict__ cb, const unsigned short* __restrict__ Wb,
    unsigned short* __restrict__ xcb, float* __restrict__ dbc)
{
    __shared__ unsigned short sA[16 * 1024];   // 32 KB, swizzled
    __shared__ float red[4][16][64];           // 16 KB
    const int tid = threadIdx.x;
    const int m0 = blockIdx.x * 16;
    // --- Phase A: conv + silu ---
    for (int task = tid; task < 16 * 128; task += 256) {
        const int rr = task >> 7;           // 0..15
        const int dd0 = (task & 127) * 8;   // 0..1016
        const int row = m0 + rr;
        const int t = row & (T_ - 1);
        float4 cw4[8];
#pragma unroll
        for (int j = 0; j < 8; ++j) cw4[j] = ((const float4*)cw)[dd0 + j];
        float acc[8];
#pragma unroll
        for (int j = 0; j < 8; ++j) acc[j] = cb[dd0 + j];
#pragma unroll
        for (int k = 0; k < DC_; ++k) {
            if (t - 3 + k >= 0) {
                const bf16x8 v = *(const bf16x8*)(xmb + (size_t)(row - 3 + k) * DI_ + dd0);
#pragma unroll
                for (int j = 0; j < 8; ++j) {
                    const float wk = (k == 0) ? cw4[j].x : (k == 1) ? cw4[j].y
                                   : (k == 2) ? cw4[j].z : cw4[j].w;
                    acc[j] += wk * bs2f((unsigned short)v[j]);
                }
            }
        }
        bf16x8 ov;
#pragma unroll
        for (int j = 0; j < 8; ++j) ov[j] = (short)f2bs(silu_f(acc[j]));
        *(bf16x8*)(xcb + (size_t)row * DI_ + dd0) = ov;
        const int byteoff = (rr * 2048 + dd0 * 2) ^ ((rr & 7) << 4);
        *(bf16x8*)((char*)sA + byteoff) = ov;
    }
    __syncthreads();
    // --- Phase B: xp GEMM, 4-way split-K over waves ---
    const int wid = tid >> 6, lane = tid & 63;
    const int r = lane & 15, kq = lane >> 4;
    f32x4 acc4[4] = {};
    const int k00 = wid * 256;
#pragma unroll
    for (int ks = 0; ks < 8; ++ks) {
        const int k0 = k00 + ks * 32;
        const int abyte = (r * 2048 + (k0 + kq * 8) * 2) ^ ((r & 7) << 4);
        const bf16x8 a = *(const bf16x8*)((const char*)sA + abyte);
#pragma unroll
        for (int j = 0; j < 4; ++j) {
            const bf16x8 bfr = *(const bf16x8*)(Wb + (size_t)(j * 16 + r) * DI_ + k0 + kq * 8);
            acc4[j] = __builtin_amdgcn_mfma_f32_16x16x32_bf16(a, bfr, acc4[j], 0, 0, 0);
        }
    }
#pragma unroll
    for (int j = 0; j < 4; ++j)
#pragma unroll
        for (int g = 0; g < 4; ++g)
            red[wid][kq * 4 + g][j * 16 + r] = acc4[j][g];
    __syncthreads();
    for (int i = tid; i < 1024; i += 256) {
        const int row = i >> 6, col = i & 63;
        const float s = red[0][row][col] + red[1][row][col] +
                        red[2][row][col] + red[3][row][col];
        dbc[(size_t)(m0 + row) * 64 + col] = s;
    }
}

// ---------------------------------------------------------------------------
// Fully fused selective scan: delta-projection + softplus + chunked scan +
// chunk combine + gate, in ONE kernel.
// Block = 256 thr = 16 groups of 16 lanes; group = (channel, chunk):
//   ch = blockIdx*2 + (grp>>3), c = grp&7; channel = (b,d).
// Pass0: each lane computes delta for t=n and t=n+16 (32 MAC fp32) ->
//        broadcast via width-16 shuffles.
// Pass1: local scan (h0=0), keeping cumA[t], C[t], partial ylp[t] in regs.
// Combine: LDS sequential over 8 chunks (exact linear recurrence).
// Pass2: y_t = reduce_n(ylp[t] + h_in*cumA[t]*C[t]); gate with silu(z); bf16.
// ---------------------------------------------------------------------------
__global__ __launch_bounds__(256) void scan_kernel(
    const unsigned short* __restrict__ xcb, const float* __restrict__ dbc,
    const float* __restrict__ dtw, const float* __restrict__ dtbias,
    const float* __restrict__ A_log, const float* __restrict__ Dp,
    const unsigned short* __restrict__ zs, unsigned short* __restrict__ ygb)
{
    const int tid = threadIdx.x;
    const int n = tid & 15, grp = tid >> 4;
    const int ch = blockIdx.x * 2 + (grp >> 3);   // 0..4095
    const int c = grp & 7;
    const int b = ch >> 10, d = ch & (DI_ - 1);
    const int row0 = b * T_ + c * TC_;
    // --- Pass 0: delta for t = n, n+16 ---
    float del0, del1;
    {
        const float4* Wp = (const float4*)(dtw + (size_t)d * R_);
        float4 w4[8];
#pragma unroll
        for (int q = 0; q < 8; ++q) w4[q] = Wp[q];
        const float bias = dtbias[d];
#pragma unroll
        for (int half = 0; half < 2; ++half) {
            const int row = row0 + n + half * 16;
            const float4* Ap = (const float4*)(dbc + (size_t)row * 64);
            float acc = bias;
#pragma unroll
            for (int q = 0; q < 8; ++q) {
                const float4 a4 = Ap[q];
                acc += a4.x * w4[q].x + a4.y * w4[q].y + a4.z * w4[q].z + a4.w * w4[q].w;
            }
            const float sp = softplus_f(acc);
            if (half == 0) del0 = sp; else del1 = sp;
        }
    }
    // --- Pass 1: local chunk scan ---
    const float Av = -__expf(A_log[d * N_ + n]);
    const float Dd = Dp[d];
    const float* bc = dbc + (size_t)row0 * 64;
    const unsigned short* up = xcb + (size_t)row0 * DI_ + d;
    float h = 0.f;
    float cumA[TC_], Crg[TC_], ylp[TC_];
#pragma unroll
    for (int t = 0; t < TC_; ++t) {
        const float dt_t = (t < 16) ? __shfl(del0, t, 16) : __shfl(del1, t - 16, 16);
        const float ut = bs2f(up[(size_t)t * DI_]);
        const float Bn = bc[t * 64 + R_ + n];
        const float Cn = bc[t * 64 + R_ + N_ + n];
        const float dA = __expf(dt_t * Av);
        h = dA * h + dt_t * Bn * ut;
        cumA[t] = (t == 0) ? dA : cumA[t - 1] * dA;
        Crg[t] = Cn;
        ylp[t] = h * Cn + ((n == 0) ? ut * Dd : 0.f);
    }
    // --- chunk combine (per channel, sequential over 8 chunks) ---
    __shared__ float Pl[16][17], Sl[16][17];
    Pl[grp][n] = cumA[TC_ - 1];
    Sl[grp][n] = h;
    __syncthreads();
    if ((grp & 7) == 0) {
        float hin = 0.f;
#pragma unroll
        for (int cc = 0; cc < CH_; ++cc) {
            const float t2 = Pl[grp + cc][n] * hin + Sl[grp + cc][n];
            Sl[grp + cc][n] = hin;
            hin = t2;
        }
    }
    __syncthreads();
    const float hin = Sl[grp][n];
    // --- Pass 2: finalize + gate ---
    unsigned short* yp = ygb + (size_t)row0 * DI_ + d;
    const unsigned short* zp = zs + (size_t)row0 * DI_ + d;
#pragma unroll
    for (int t = 0; t < TC_; ++t) {
        float v = ylp[t] + hin * cumA[t] * Crg[t];
        v += __shfl_xor(v, 1);
        v += __shfl_xor(v, 2);
        v += __shfl_xor(v, 4);
        v += __shfl_xor(v, 8);
        if (n == 0) {
            const float zv = bs2f(zp[(size_t)t * DI_]);
            yp[(size_t)t * DI_] = f2bs(v * zv);
        }
    }
}

// ---------------------------------------------------------------------------
// Heads
// ---------------------------------------------------------------------------
__global__ __launch_bounds__(256) void heads_kernel(
    const float* __restrict__ xn,
    const float* __restrict__ ps_w, const float* __restrict__ ps_b,
    const float* __restrict__ pa_w, const float* __restrict__ pa_b,
    float* __restrict__ out)
{
    const int idx = blockIdx.x * 4 + (threadIdx.x >> 6);
    const int lane = threadIdx.x & 63;
    const int bl = idx / 23, j = idx % 23;
    const float* tok;
    const float* wrow;
    float bias;
    float* dst;
    if (j < SD_) {
        tok = xn + ((size_t)bl * 4 + 3) * D_;
        wrow = ps_w + (size_t)j * D_;
        bias = ps_b[j];
        dst = out + (size_t)bl * SD_ + j;
    } else {
        const int jj = j - SD_;
        tok = xn + ((size_t)bl * 4 + 2) * D_;
        wrow = pa_w + (size_t)jj * D_;
        bias = pa_b[jj];
        dst = out + (size_t)B_ * L_ * SD_ + (size_t)bl * AD_ + jj;
    }
    float s = 0.f;
    for (int dd = lane; dd < D_; dd += 64) s += tok[dd] * wrow[dd];
#pragma unroll
    for (int off = 1; off < 64; off <<= 1) s += __shfl_xor(s, off);
    if (lane == 0) *dst = s + bias;
}

// ---------------------------------------------------------------------------
extern "C" void kernel_launch(void* const* d_in, const int* in_sizes, int n_in,
                              void* d_out, int out_size, void* d_ws, size_t ws_size,
                              hipStream_t stream)
{
    const float* states  = (const float*)d_in[0];
    const float* actions = (const float*)d_in[1];
    const float* rtg     = (const float*)d_in[2];
    const float* ctg     = (const float*)d_in[3];
    const int*   ts      = (const int*)d_in[4];
    const float* es_w = (const float*)d_in[5];  const float* es_b = (const float*)d_in[6];
    const float* ea_w = (const float*)d_in[7];  const float* ea_b = (const float*)d_in[8];
    const float* er_w = (const float*)d_in[9];  const float* er_b = (const float*)d_in[10];
    const float* ec_w = (const float*)d_in[11]; const float* ec_b = (const float*)d_in[12];
    const float* et_w = (const float*)d_in[13];
    const float* ln_w = (const float*)d_in[14]; const float* ln_b = (const float*)d_in[15];
    const float* in_w = (const float*)d_in[16];
    const float* conv_w = (const float*)d_in[17]; const float* conv_b = (const float*)d_in[18];
    const float* xp_w = (const float*)d_in[19];
    const float* dtp_w = (const float*)d_in[20]; const float* dtp_b = (const float*)d_in[21];
    const float* A_log = (const float*)d_in[22]; const float* Dp = (const float*)d_in[23];
    const float* out_w = (const float*)d_in[24];
    const float* fn_w = (const float*)d_in[25]; const float* fn_b = (const float*)d_in[26];
    const float* ps_w = (const float*)d_in[27]; const float* ps_b = (const float*)d_in[28];
    const float* pa_w = (const float*)d_in[29]; const float* pa_b = (const float*)d_in[30];
    float* out = (float*)d_out;

    // workspace layout
    float* ws   = (float*)d_ws;
    float* x    = ws;                    // 524288 f32
    float* xn   = x + 524288;            // 524288 f32 (final LN out)
    float* p    = xn + 524288;           // 1048576 f32 (out_proj partials p0|p1)
    float* dbc  = p + 1048576;           // 65536 f32
    unsigned short* xnb = (unsigned short*)(dbc + 65536);  // 524288 bf16
    unsigned short* xmb = xnb + 524288;                    // 1048576 bf16
    unsigned short* xcb = xmb + 1048576;                   // 1048576 bf16
    unsigned short* zs  = xcb + 1048576;                   // 1048576 bf16
    unsigned short* ygb = zs + 1048576;                    // 1048576 bf16
    unsigned short* wb  = ygb + 1048576;                   // 6553600 bf16
    unsigned short* wb_in  = wb;
    unsigned short* wb_out = wb + NW_IN;
    unsigned short* wb_xp  = wb + NW_IN + NW_OUT;

    wcvt_kernel<<<(NW_TOT / 4 + 255) / 256, 256, 0, stream>>>(in_w, out_w, xp_w, wb);
    embed_kernel<<<B_ * L_, D_, 0, stream>>>(states, actions, rtg, ctg, ts,
        es_w, es_b, ea_w, ea_b, er_w, er_b, ec_w, ec_b, et_w, x);

    for (int i = 0; i < NL_; ++i) {
        if (i == 0)
            ln2_kernel<0><<<B_ * T_, 256, 0, stream>>>(
                x, nullptr, nullptr, ln_w, ln_b, xnb);
        else
            ln2_kernel<1><<<B_ * T_, 256, 0, stream>>>(
                x, p, p + 524288, ln_w + i * D_, ln_b + i * D_, xnb);
        // in_proj: (1024 x 2048 x 512) -> xmb bf16 | zs=silu(z) bf16
        gemm3<2, 2, 3, 512><<<dim3(32, 16), 256, 0, stream>>>(
            xnb, D_, wb_in + (size_t)i * 2 * DI_ * D_, D_, nullptr, xmb, zs, 2 * DI_);
        // conv+silu fused with xp GEMM -> xcb bf16, dbc fp32
        convxp_kernel<<<64, 256, 0, stream>>>(
            xmb, conv_w + i * DI_ * DC_, conv_b + i * DI_,
            wb_xp + (size_t)i * 64 * DI_, xcb, dbc);
        // fused delta + chunked scan + gate -> ygb bf16
        scan_kernel<<<2048, 256, 0, stream>>>(
            xcb, dbc, dtp_w + (size_t)i * DI_ * R_, dtp_b + i * DI_,
            A_log + (size_t)i * DI_ * N_, Dp + i * DI_, zs, ygb);
        // out_proj split-K=2: p[z] = yg[:, z*512:+512] @ W[:, z*512:+512]^T
        gemm3<2, 2, 4, 512><<<dim3(8, 16, 2), 256, 0, stream>>>(
            ygb, DI_, wb_out + (size_t)i * D_ * DI_, DI_, p, nullptr, nullptr, D_);
    }

    ln2_kernel<2><<<B_ * T_, 256, 0, stream>>>(x, p, p + 524288, fn_w, fn_b, xn);
    heads_kernel<<<(B_ * L_ * 23) / 4, 256, 0, stream>>>(xn, ps_w, ps_b, pa_w, pa_b, out);
}

// Round 5
// 511.699 us; speedup vs baseline: 1.1157x; 1.1157x over previous
//
#include <hip/hip_runtime.h>
#include <math.h>

#define B_ 4
#define L_ 64
#define D_ 512
#define DI_ 1024
#define N_ 16
#define DC_ 4
#define R_ 32
#define NL_ 4
#define SD_ 17
#define AD_ 6
#define T_ 256   // 4*L
#define CH_ 8    // scan chunks
#define TC_ 32   // T_/CH_

// bf16 weight segment sizes (elements)
#define NW_IN  (NL_ * 2 * DI_ * D_)   // 4194304
#define NW_OUT (NL_ * D_ * DI_)       // 2097152
#define NW_XP  (NL_ * 64 * DI_)       // 262144
#define NW_TOT (NW_IN + NW_OUT + NW_XP)  // 6553600

typedef short bf16x8 __attribute__((ext_vector_type(8)));
typedef float f32x4 __attribute__((ext_vector_type(4)));

__device__ __forceinline__ float silu_f(float v) { return v / (1.f + __expf(-v)); }
__device__ __forceinline__ float softplus_f(float v) {
    return fmaxf(v, 0.f) + log1pf(__expf(-fabsf(v)));
}
__device__ __forceinline__ unsigned short f2bs(float f) {
    unsigned u = __float_as_uint(f);
    u += 0x7fffu + ((u >> 16) & 1u);
    return (unsigned short)(u >> 16);
}
__device__ __forceinline__ float bs2f(unsigned short s) {
    return __uint_as_float(((unsigned)s) << 16);
}

// ---------------------------------------------------------------------------
// One-time: weights fp32 -> bf16 (in_w | out_w | xp_w)
// ---------------------------------------------------------------------------
__global__ __launch_bounds__(256) void wcvt_kernel(
    const float* __restrict__ in_w, const float* __restrict__ out_w,
    const float* __restrict__ xp_w, unsigned short* __restrict__ wb)
{
    const int i = blockIdx.x * 256 + threadIdx.x;   // float4 index
    if (i >= NW_TOT / 4) return;
    const int e = i * 4;
    const float* src; int off;
    if (e < NW_IN)               { src = in_w;  off = e; }
    else if (e < NW_IN + NW_OUT) { src = out_w; off = e - NW_IN; }
    else                         { src = xp_w;  off = e - NW_IN - NW_OUT; }
    const float4 v = *(const float4*)(src + off);
    ushort4 o;
    o.x = f2bs(v.x); o.y = f2bs(v.y); o.z = f2bs(v.z); o.w = f2bs(v.w);
    *(ushort4*)(wb + e) = o;
}

// ---------------------------------------------------------------------------
// Embedding
// ---------------------------------------------------------------------------
__global__ __launch_bounds__(512) void embed_kernel(
    const float* __restrict__ states, const float* __restrict__ actions,
    const float* __restrict__ rtg, const float* __restrict__ ctg,
    const int* __restrict__ ts,
    const float* __restrict__ es_w, const float* __restrict__ es_b,
    const float* __restrict__ ea_w, const float* __restrict__ ea_b,
    const float* __restrict__ er_w, const float* __restrict__ er_b,
    const float* __restrict__ ec_w, const float* __restrict__ ec_b,
    const float* __restrict__ et_w, float* __restrict__ x)
{
    const int bl = blockIdx.x;
    const int d = threadIdx.x;
    const float te = et_w[(size_t)ts[bl] * D_ + d];
    const float r = rtg[bl] * er_w[d] + er_b[d] + te;
    const float c = ctg[bl] * ec_w[d] + ec_b[d] + te;
    float s = es_b[d] + te;
#pragma unroll
    for (int k = 0; k < SD_; ++k) s += states[bl * SD_ + k] * es_w[d * SD_ + k];
    float a = ea_b[d] + te;
#pragma unroll
    for (int k = 0; k < AD_; ++k) a += actions[bl * AD_ + k] * ea_w[d * AD_ + k];
    float* xp = x + (size_t)bl * 4 * D_;
    xp[0 * D_ + d] = r;
    xp[1 * D_ + d] = c;
    xp[2 * D_ + d] = s;
    xp[3 * D_ + d] = a;
}

// ---------------------------------------------------------------------------
// LayerNorm (+ optional residual partial sum from split-K out_proj).
// MODE 0: ln(x) -> bf16 out.  MODE 1: x += p0+p1 (stored), ln -> bf16 out.
// MODE 2: x += p0+p1, ln -> fp32 out.
// ---------------------------------------------------------------------------
template <int MODE>
__global__ __launch_bounds__(256) void ln2_kernel(
    float* __restrict__ x, const float* __restrict__ p0,
    const float* __restrict__ p1,
    const float* __restrict__ w, const float* __restrict__ b,
    void* __restrict__ o_)
{
    const int tok = blockIdx.x;
    const int tid = threadIdx.x;
    float2 v = reinterpret_cast<float2*>(x + (size_t)tok * D_)[tid];
    if (MODE >= 1) {
        const float2 a0 = reinterpret_cast<const float2*>(p0 + (size_t)tok * D_)[tid];
        const float2 a1 = reinterpret_cast<const float2*>(p1 + (size_t)tok * D_)[tid];
        v.x += a0.x + a1.x;
        v.y += a0.y + a1.y;
        reinterpret_cast<float2*>(x + (size_t)tok * D_)[tid] = v;
    }
    float s = v.x + v.y;
#pragma unroll
    for (int off = 1; off < 64; off <<= 1) s += __shfl_xor(s, off);
    __shared__ float red[8];
    const int wv = tid >> 6;
    if ((tid & 63) == 0) red[wv] = s;
    __syncthreads();
    const float mean = (red[0] + red[1] + red[2] + red[3]) * (1.f / D_);
    const float dx = v.x - mean, dy = v.y - mean;
    float q = dx * dx + dy * dy;
#pragma unroll
    for (int off = 1; off < 64; off <<= 1) q += __shfl_xor(q, off);
    if ((tid & 63) == 0) red[4 + wv] = q;
    __syncthreads();
    const float var = (red[4] + red[5] + red[6] + red[7]) * (1.f / D_);
    const float r = rsqrtf(var + 1e-5f);
    const int d0 = tid * 2;
    const float o0 = dx * r * w[d0] + b[d0];
    const float o1 = dy * r * w[d0 + 1] + b[d0 + 1];
    if (MODE == 2) {
        float* o = (float*)o_;
        o[(size_t)tok * D_ + d0] = o0;
        o[(size_t)tok * D_ + d0 + 1] = o1;
    } else {
        unsigned short* o = (unsigned short*)o_;
        o[(size_t)tok * D_ + d0] = f2bs(o0);
        o[(size_t)tok * D_ + d0 + 1] = f2bs(o1);
    }
}

// ---------------------------------------------------------------------------
// MFMA bf16 GEMM, A and W both bf16, K compile-time.
// EPI 3: in_proj split store (col<DI -> xmb bf16; col>=DI -> zs=silu bf16)
// EPI 4: split-K partial store to C + blockIdx.z*(1024*512), k base z*KT
// EPI 0: plain fp32 store
// ---------------------------------------------------------------------------
template <int MR, int NR, int EPI, int KT>
__global__ __launch_bounds__(256) void gemm3(
    const unsigned short* __restrict__ A, int lda,
    const unsigned short* __restrict__ W, int ldw,
    float* __restrict__ C, unsigned short* __restrict__ Cb1,
    unsigned short* __restrict__ Cb2, int N)
{
    const int lane = threadIdx.x & 63, wid = threadIdx.x >> 6;
    const int r = lane & 15, kq = lane >> 4;
    const int wm = blockIdx.y * (2 * MR * 16) + (wid >> 1) * (MR * 16);
    const int wn = blockIdx.x * (2 * NR * 16) + (wid & 1) * (NR * 16);
    const int kb = (EPI == 4) ? blockIdx.z * KT : 0;
    f32x4 acc[MR][NR] = {};
#pragma unroll 4
    for (int k0 = 0; k0 < KT; k0 += 32) {
        bf16x8 a[MR], b[NR];
#pragma unroll
        for (int i = 0; i < MR; ++i)
            a[i] = *(const bf16x8*)(A + (size_t)(wm + i * 16 + r) * lda + kb + k0 + kq * 8);
#pragma unroll
        for (int j = 0; j < NR; ++j)
            b[j] = *(const bf16x8*)(W + (size_t)(wn + j * 16 + r) * ldw + kb + k0 + kq * 8);
#pragma unroll
        for (int i = 0; i < MR; ++i)
#pragma unroll
            for (int j = 0; j < NR; ++j)
                acc[i][j] = __builtin_amdgcn_mfma_f32_16x16x32_bf16(a[i], b[j], acc[i][j], 0, 0, 0);
    }
    // C/D layout: col = lane&15, row = (lane>>4)*4 + reg
#pragma unroll
    for (int i = 0; i < MR; ++i)
#pragma unroll
        for (int j = 0; j < NR; ++j)
#pragma unroll
            for (int g = 0; g < 4; ++g) {
                const int row = wm + i * 16 + kq * 4 + g;
                const int col = wn + j * 16 + r;
                const float val = acc[i][j][g];
                if (EPI == 3) {
                    if (col < DI_) Cb1[(size_t)row * DI_ + col] = f2bs(val);
                    else Cb2[(size_t)row * DI_ + (col - DI_)] = f2bs(silu_f(val));
                } else if (EPI == 4) {
                    C[(size_t)blockIdx.z * (1024 * 512) + (size_t)row * 512 + col] = val;
                } else {
                    C[(size_t)row * N + col] = val;
                }
            }
}

// ---------------------------------------------------------------------------
// Fused conv1d+silu + xp GEMM (unchanged from R4 — not the regression).
// ---------------------------------------------------------------------------
__global__ __launch_bounds__(256) void convxp_kernel(
    const unsigned short* __restrict__ xmb, const float* __restrict__ cw,
    const float* __restrict__ cb, const unsigned short* __restrict__ Wb,
    unsigned short* __restrict__ xcb, float* __restrict__ dbc)
{
    __shared__ unsigned short sA[16 * 1024];   // 32 KB, swizzled
    __shared__ float red[4][16][64];           // 16 KB
    const int tid = threadIdx.x;
    const int m0 = blockIdx.x * 16;
    // --- Phase A: conv + silu ---
    for (int task = tid; task < 16 * 128; task += 256) {
        const int rr = task >> 7;           // 0..15
        const int dd0 = (task & 127) * 8;   // 0..1016
        const int row = m0 + rr;
        const int t = row & (T_ - 1);
        float4 cw4[8];
#pragma unroll
        for (int j = 0; j < 8; ++j) cw4[j] = ((const float4*)cw)[dd0 + j];
        float acc[8];
#pragma unroll
        for (int j = 0; j < 8; ++j) acc[j] = cb[dd0 + j];
#pragma unroll
        for (int k = 0; k < DC_; ++k) {
            if (t - 3 + k >= 0) {
                const bf16x8 v = *(const bf16x8*)(xmb + (size_t)(row - 3 + k) * DI_ + dd0);
#pragma unroll
                for (int j = 0; j < 8; ++j) {
                    const float wk = (k == 0) ? cw4[j].x : (k == 1) ? cw4[j].y
                                   : (k == 2) ? cw4[j].z : cw4[j].w;
                    acc[j] += wk * bs2f((unsigned short)v[j]);
                }
            }
        }
        bf16x8 ov;
#pragma unroll
        for (int j = 0; j < 8; ++j) ov[j] = (short)f2bs(silu_f(acc[j]));
        *(bf16x8*)(xcb + (size_t)row * DI_ + dd0) = ov;
        const int byteoff = (rr * 2048 + dd0 * 2) ^ ((rr & 7) << 4);
        *(bf16x8*)((char*)sA + byteoff) = ov;
    }
    __syncthreads();
    // --- Phase B: xp GEMM, 4-way split-K over waves ---
    const int wid = tid >> 6, lane = tid & 63;
    const int r = lane & 15, kq = lane >> 4;
    f32x4 acc4[4] = {};
    const int k00 = wid * 256;
#pragma unroll
    for (int ks = 0; ks < 8; ++ks) {
        const int k0 = k00 + ks * 32;
        const int abyte = (r * 2048 + (k0 + kq * 8) * 2) ^ ((r & 7) << 4);
        const bf16x8 a = *(const bf16x8*)((const char*)sA + abyte);
#pragma unroll
        for (int j = 0; j < 4; ++j) {
            const bf16x8 bfr = *(const bf16x8*)(Wb + (size_t)(j * 16 + r) * DI_ + k0 + kq * 8);
            acc4[j] = __builtin_amdgcn_mfma_f32_16x16x32_bf16(a, bfr, acc4[j], 0, 0, 0);
        }
    }
#pragma unroll
    for (int j = 0; j < 4; ++j)
#pragma unroll
        for (int g = 0; g < 4; ++g)
            red[wid][kq * 4 + g][j * 16 + r] = acc4[j][g];
    __syncthreads();
    for (int i = tid; i < 1024; i += 256) {
        const int row = i >> 6, col = i & 63;
        const float s = red[0][row][col] + red[1][row][col] +
                        red[2][row][col] + red[3][row][col];
        dbc[(size_t)(m0 + row) * 64 + col] = s;
    }
}

// ---------------------------------------------------------------------------
// Fused selective scan, SPILL-FREE two-sweep version.
// Block = 16 groups of 16 lanes; group = (channel, chunk); 2 channels/block.
// Pass 0: delta for t=n, n+16 (32 fp32 MACs) -> kept in 2 regs, shfl-bcast.
// Sweep 1: local scan (h0=0) -> only final h and decay product Pp (2 regs).
// Combine: in-block LDS sequential over the 8 chunks (exact).
// Sweep 2: re-scan from h_in, recompute dA, emit y, gate with silu(z).
// No per-timestep arrays -> no scratch spill (R4 lesson: 96-float arrays
// spilled -> 14 MB scratch traffic, 81 us; VALU recompute is ~free at 20%).
// ---------------------------------------------------------------------------
__global__ __launch_bounds__(256) void scan_kernel(
    const unsigned short* __restrict__ xcb, const float* __restrict__ dbc,
    const float* __restrict__ dtw, const float* __restrict__ dtbias,
    const float* __restrict__ A_log, const float* __restrict__ Dp,
    const unsigned short* __restrict__ zs, unsigned short* __restrict__ ygb)
{
    const int tid = threadIdx.x;
    const int n = tid & 15, grp = tid >> 4;
    const int ch = blockIdx.x * 2 + (grp >> 3);   // 0..4095
    const int c = grp & 7;
    const int b = ch >> 10, d = ch & (DI_ - 1);
    const int row0 = b * T_ + c * TC_;
    // --- Pass 0: delta for t = n, n+16 ---
    float del0, del1;
    {
        const float4* Wp = (const float4*)(dtw + (size_t)d * R_);
        float4 w4[8];
#pragma unroll
        for (int q = 0; q < 8; ++q) w4[q] = Wp[q];
        const float bias = dtbias[d];
#pragma unroll
        for (int half = 0; half < 2; ++half) {
            const int row = row0 + n + half * 16;
            const float4* Ap = (const float4*)(dbc + (size_t)row * 64);
            float acc = bias;
#pragma unroll
            for (int q = 0; q < 8; ++q) {
                const float4 a4 = Ap[q];
                acc += a4.x * w4[q].x + a4.y * w4[q].y + a4.z * w4[q].z + a4.w * w4[q].w;
            }
            const float sp = softplus_f(acc);
            if (half == 0) del0 = sp; else del1 = sp;
        }
    }
    const float Av = -__expf(A_log[d * N_ + n]);
    const float Dd = Dp[d];
    const float* bc = dbc + (size_t)row0 * 64;
    const unsigned short* up = xcb + (size_t)row0 * DI_ + d;
    // --- Sweep 1: local chunk scan (state: h, Pp only) ---
    float h = 0.f, Pp = 1.f;
#pragma unroll 8
    for (int t = 0; t < TC_; ++t) {
        const float dt_t = (t < 16) ? __shfl(del0, t, 16) : __shfl(del1, t - 16, 16);
        const float ut = bs2f(up[(size_t)t * DI_]);
        const float Bn = bc[t * 64 + R_ + n];
        const float dA = __expf(dt_t * Av);
        h = dA * h + dt_t * Bn * ut;
        Pp *= dA;
    }
    // --- chunk combine (per channel, sequential over 8 chunks) ---
    __shared__ float Pl[16][17], Sl[16][17];
    Pl[grp][n] = Pp;
    Sl[grp][n] = h;
    __syncthreads();
    if ((grp & 7) == 0) {
        float hin = 0.f;
#pragma unroll
        for (int cc = 0; cc < CH_; ++cc) {
            const float t2 = Pl[grp + cc][n] * hin + Sl[grp + cc][n];
            Sl[grp + cc][n] = hin;
            hin = t2;
        }
    }
    __syncthreads();
    // --- Sweep 2: re-scan from h_in, emit gated y ---
    h = Sl[grp][n];
    unsigned short* yp = ygb + (size_t)row0 * DI_ + d;
    const unsigned short* zp = zs + (size_t)row0 * DI_ + d;
#pragma unroll 8
    for (int t = 0; t < TC_; ++t) {
        const float dt_t = (t < 16) ? __shfl(del0, t, 16) : __shfl(del1, t - 16, 16);
        const float ut = bs2f(up[(size_t)t * DI_]);
        const float Bn = bc[t * 64 + R_ + n];
        const float Cn = bc[t * 64 + R_ + N_ + n];
        h = __expf(dt_t * Av) * h + dt_t * Bn * ut;
        float v = h * Cn + ((n == 0) ? ut * Dd : 0.f);
        v += __shfl_xor(v, 1);
        v += __shfl_xor(v, 2);
        v += __shfl_xor(v, 4);
        v += __shfl_xor(v, 8);
        if (n == 0) {
            const float zv = bs2f(zp[(size_t)t * DI_]);
            yp[(size_t)t * DI_] = f2bs(v * zv);
        }
    }
}

// ---------------------------------------------------------------------------
// Heads
// ---------------------------------------------------------------------------
__global__ __launch_bounds__(256) void heads_kernel(
    const float* __restrict__ xn,
    const float* __restrict__ ps_w, const float* __restrict__ ps_b,
    const float* __restrict__ pa_w, const float* __restrict__ pa_b,
    float* __restrict__ out)
{
    const int idx = blockIdx.x * 4 + (threadIdx.x >> 6);
    const int lane = threadIdx.x & 63;
    const int bl = idx / 23, j = idx % 23;
    const float* tok;
    const float* wrow;
    float bias;
    float* dst;
    if (j < SD_) {
        tok = xn + ((size_t)bl * 4 + 3) * D_;
        wrow = ps_w + (size_t)j * D_;
        bias = ps_b[j];
        dst = out + (size_t)bl * SD_ + j;
    } else {
        const int jj = j - SD_;
        tok = xn + ((size_t)bl * 4 + 2) * D_;
        wrow = pa_w + (size_t)jj * D_;
        bias = pa_b[jj];
        dst = out + (size_t)B_ * L_ * SD_ + (size_t)bl * AD_ + jj;
    }
    float s = 0.f;
    for (int dd = lane; dd < D_; dd += 64) s += tok[dd] * wrow[dd];
#pragma unroll
    for (int off = 1; off < 64; off <<= 1) s += __shfl_xor(s, off);
    if (lane == 0) *dst = s + bias;
}

// ---------------------------------------------------------------------------
extern "C" void kernel_launch(void* const* d_in, const int* in_sizes, int n_in,
                              void* d_out, int out_size, void* d_ws, size_t ws_size,
                              hipStream_t stream)
{
    const float* states  = (const float*)d_in[0];
    const float* actions = (const float*)d_in[1];
    const float* rtg     = (const float*)d_in[2];
    const float* ctg     = (const float*)d_in[3];
    const int*   ts      = (const int*)d_in[4];
    const float* es_w = (const float*)d_in[5];  const float* es_b = (const float*)d_in[6];
    const float* ea_w = (const float*)d_in[7];  const float* ea_b = (const float*)d_in[8];
    const float* er_w = (const float*)d_in[9];  const float* er_b = (const float*)d_in[10];
    const float* ec_w = (const float*)d_in[11]; const float* ec_b = (const float*)d_in[12];
    const float* et_w = (const float*)d_in[13];
    const float* ln_w = (const float*)d_in[14]; const float* ln_b = (const float*)d_in[15];
    const float* in_w = (const float*)d_in[16];
    const float* conv_w = (const float*)d_in[17]; const float* conv_b = (const float*)d_in[18];
    const float* xp_w = (const float*)d_in[19];
    const float* dtp_w = (const float*)d_in[20]; const float* dtp_b = (const float*)d_in[21];
    const float* A_log = (const float*)d_in[22]; const float* Dp = (const float*)d_in[23];
    const float* out_w = (const float*)d_in[24];
    const float* fn_w = (const float*)d_in[25]; const float* fn_b = (const float*)d_in[26];
    const float* ps_w = (const float*)d_in[27]; const float* ps_b = (const float*)d_in[28];
    const float* pa_w = (const float*)d_in[29]; const float* pa_b = (const float*)d_in[30];
    float* out = (float*)d_out;

    // workspace layout
    float* ws   = (float*)d_ws;
    float* x    = ws;                    // 524288 f32
    float* xn   = x + 524288;            // 524288 f32 (final LN out)
    float* p    = xn + 524288;           // 1048576 f32 (out_proj partials p0|p1)
    float* dbc  = p + 1048576;           // 65536 f32
    unsigned short* xnb = (unsigned short*)(dbc + 65536);  // 524288 bf16
    unsigned short* xmb = xnb + 524288;                    // 1048576 bf16
    unsigned short* xcb = xmb + 1048576;                   // 1048576 bf16
    unsigned short* zs  = xcb + 1048576;                   // 1048576 bf16
    unsigned short* ygb = zs + 1048576;                    // 1048576 bf16
    unsigned short* wb  = ygb + 1048576;                   // 6553600 bf16
    unsigned short* wb_in  = wb;
    unsigned short* wb_out = wb + NW_IN;
    unsigned short* wb_xp  = wb + NW_IN + NW_OUT;

    wcvt_kernel<<<(NW_TOT / 4 + 255) / 256, 256, 0, stream>>>(in_w, out_w, xp_w, wb);
    embed_kernel<<<B_ * L_, D_, 0, stream>>>(states, actions, rtg, ctg, ts,
        es_w, es_b, ea_w, ea_b, er_w, er_b, ec_w, ec_b, et_w, x);

    for (int i = 0; i < NL_; ++i) {
        if (i == 0)
            ln2_kernel<0><<<B_ * T_, 256, 0, stream>>>(
                x, nullptr, nullptr, ln_w, ln_b, xnb);
        else
            ln2_kernel<1><<<B_ * T_, 256, 0, stream>>>(
                x, p, p + 524288, ln_w + i * D_, ln_b + i * D_, xnb);
        // in_proj: (1024 x 2048 x 512) -> xmb bf16 | zs=silu(z) bf16
        gemm3<2, 2, 3, 512><<<dim3(32, 16), 256, 0, stream>>>(
            xnb, D_, wb_in + (size_t)i * 2 * DI_ * D_, D_, nullptr, xmb, zs, 2 * DI_);
        // conv+silu fused with xp GEMM -> xcb bf16, dbc fp32
        convxp_kernel<<<64, 256, 0, stream>>>(
            xmb, conv_w + i * DI_ * DC_, conv_b + i * DI_,
            wb_xp + (size_t)i * 64 * DI_, xcb, dbc);
        // fused delta + chunked scan + gate -> ygb bf16
        scan_kernel<<<2048, 256, 0, stream>>>(
            xcb, dbc, dtp_w + (size_t)i * DI_ * R_, dtp_b + i * DI_,
            A_log + (size_t)i * DI_ * N_, Dp + i * DI_, zs, ygb);
        // out_proj split-K=2: p[z] = yg[:, z*512:+512] @ W[:, z*512:+512]^T
        gemm3<2, 2, 4, 512><<<dim3(8, 16, 2), 256, 0, stream>>>(
            ygb, DI_, wb_out + (size_t)i * D_ * DI_, DI_, p, nullptr, nullptr, D_);
    }

    ln2_kernel<2><<<B_ * T_, 256, 0, stream>>>(x, p, p + 524288, fn_w, fn_b, xn);
    heads_kernel<<<(B_ * L_ * 23) / 4, 256, 0, stream>>>(xn, ps_w, ps_b, pa_w, pa_b, out);
}

// Round 6
// 455.971 us; speedup vs baseline: 1.2521x; 1.1222x over previous
//
#include <hip/hip_runtime.h>
#include <math.h>

#define B_ 4
#define L_ 64
#define D_ 512
#define DI_ 1024
#define N_ 16
#define DC_ 4
#define R_ 32
#define NL_ 4
#define SD_ 17
#define AD_ 6
#define T_ 256    // 4*L
#define CH2_ 16   // scan chunks (d-per-lane layout)
#define TC2_ 16   // T_/CH2_

// bf16 weight segment sizes (elements)
#define NW_IN  (NL_ * 2 * DI_ * D_)   // 4194304
#define NW_OUT (NL_ * D_ * DI_)       // 2097152
#define NW_XP  (NL_ * 64 * DI_)       // 262144
#define NW_TOT (NW_IN + NW_OUT + NW_XP)  // 6553600

typedef short bf16x8 __attribute__((ext_vector_type(8)));
typedef float f32x4 __attribute__((ext_vector_type(4)));

__device__ __forceinline__ float silu_f(float v) { return v / (1.f + __expf(-v)); }
__device__ __forceinline__ float softplus_f(float v) {
    return fmaxf(v, 0.f) + log1pf(__expf(-fabsf(v)));
}
__device__ __forceinline__ unsigned short f2bs(float f) {
    unsigned u = __float_as_uint(f);
    u += 0x7fffu + ((u >> 16) & 1u);
    return (unsigned short)(u >> 16);
}
__device__ __forceinline__ float bs2f(unsigned short s) {
    return __uint_as_float(((unsigned)s) << 16);
}

// ---------------------------------------------------------------------------
// One-time: weights fp32 -> bf16 (in_w | out_w | xp_w)
// ---------------------------------------------------------------------------
__global__ __launch_bounds__(256) void wcvt_kernel(
    const float* __restrict__ in_w, const float* __restrict__ out_w,
    const float* __restrict__ xp_w, unsigned short* __restrict__ wb)
{
    const int i = blockIdx.x * 256 + threadIdx.x;   // float4 index
    if (i >= NW_TOT / 4) return;
    const int e = i * 4;
    const float* src; int off;
    if (e < NW_IN)               { src = in_w;  off = e; }
    else if (e < NW_IN + NW_OUT) { src = out_w; off = e - NW_IN; }
    else                         { src = xp_w;  off = e - NW_IN - NW_OUT; }
    const float4 v = *(const float4*)(src + off);
    ushort4 o;
    o.x = f2bs(v.x); o.y = f2bs(v.y); o.z = f2bs(v.z); o.w = f2bs(v.w);
    *(ushort4*)(wb + e) = o;
}

// ---------------------------------------------------------------------------
// Embedding
// ---------------------------------------------------------------------------
__global__ __launch_bounds__(512) void embed_kernel(
    const float* __restrict__ states, const float* __restrict__ actions,
    const float* __restrict__ rtg, const float* __restrict__ ctg,
    const int* __restrict__ ts,
    const float* __restrict__ es_w, const float* __restrict__ es_b,
    const float* __restrict__ ea_w, const float* __restrict__ ea_b,
    const float* __restrict__ er_w, const float* __restrict__ er_b,
    const float* __restrict__ ec_w, const float* __restrict__ ec_b,
    const float* __restrict__ et_w, float* __restrict__ x)
{
    const int bl = blockIdx.x;
    const int d = threadIdx.x;
    const float te = et_w[(size_t)ts[bl] * D_ + d];
    const float r = rtg[bl] * er_w[d] + er_b[d] + te;
    const float c = ctg[bl] * ec_w[d] + ec_b[d] + te;
    float s = es_b[d] + te;
#pragma unroll
    for (int k = 0; k < SD_; ++k) s += states[bl * SD_ + k] * es_w[d * SD_ + k];
    float a = ea_b[d] + te;
#pragma unroll
    for (int k = 0; k < AD_; ++k) a += actions[bl * AD_ + k] * ea_w[d * AD_ + k];
    float* xp = x + (size_t)bl * 4 * D_;
    xp[0 * D_ + d] = r;
    xp[1 * D_ + d] = c;
    xp[2 * D_ + d] = s;
    xp[3 * D_ + d] = a;
}

// ---------------------------------------------------------------------------
// LayerNorm (+ optional residual partial sum from split-K out_proj).
// MODE 0: ln(x) -> bf16 out.  MODE 1: x += p0+p1 (stored), ln -> bf16 out.
// MODE 2: x += p0+p1, ln -> fp32 out.
// ---------------------------------------------------------------------------
template <int MODE>
__global__ __launch_bounds__(256) void ln2_kernel(
    float* __restrict__ x, const float* __restrict__ p0,
    const float* __restrict__ p1,
    const float* __restrict__ w, const float* __restrict__ b,
    void* __restrict__ o_)
{
    const int tok = blockIdx.x;
    const int tid = threadIdx.x;
    float2 v = reinterpret_cast<float2*>(x + (size_t)tok * D_)[tid];
    if (MODE >= 1) {
        const float2 a0 = reinterpret_cast<const float2*>(p0 + (size_t)tok * D_)[tid];
        const float2 a1 = reinterpret_cast<const float2*>(p1 + (size_t)tok * D_)[tid];
        v.x += a0.x + a1.x;
        v.y += a0.y + a1.y;
        reinterpret_cast<float2*>(x + (size_t)tok * D_)[tid] = v;
    }
    float s = v.x + v.y;
#pragma unroll
    for (int off = 1; off < 64; off <<= 1) s += __shfl_xor(s, off);
    __shared__ float red[8];
    const int wv = tid >> 6;
    if ((tid & 63) == 0) red[wv] = s;
    __syncthreads();
    const float mean = (red[0] + red[1] + red[2] + red[3]) * (1.f / D_);
    const float dx = v.x - mean, dy = v.y - mean;
    float q = dx * dx + dy * dy;
#pragma unroll
    for (int off = 1; off < 64; off <<= 1) q += __shfl_xor(q, off);
    if ((tid & 63) == 0) red[4 + wv] = q;
    __syncthreads();
    const float var = (red[4] + red[5] + red[6] + red[7]) * (1.f / D_);
    const float r = rsqrtf(var + 1e-5f);
    const int d0 = tid * 2;
    const float o0 = dx * r * w[d0] + b[d0];
    const float o1 = dy * r * w[d0 + 1] + b[d0 + 1];
    if (MODE == 2) {
        float* o = (float*)o_;
        o[(size_t)tok * D_ + d0] = o0;
        o[(size_t)tok * D_ + d0 + 1] = o1;
    } else {
        unsigned short* o = (unsigned short*)o_;
        o[(size_t)tok * D_ + d0] = f2bs(o0);
        o[(size_t)tok * D_ + d0 + 1] = f2bs(o1);
    }
}

// ---------------------------------------------------------------------------
// MFMA bf16 GEMM, A and W both bf16, K compile-time.
// EPI 3: in_proj split store (col<DI -> xmb bf16; col>=DI -> zs=silu bf16)
// EPI 4: split-K partial store to C + blockIdx.z*(1024*512), k base z*KT
// EPI 0: plain fp32 store
// ---------------------------------------------------------------------------
template <int MR, int NR, int EPI, int KT>
__global__ __launch_bounds__(256) void gemm3(
    const unsigned short* __restrict__ A, int lda,
    const unsigned short* __restrict__ W, int ldw,
    float* __restrict__ C, unsigned short* __restrict__ Cb1,
    unsigned short* __restrict__ Cb2, int N)
{
    const int lane = threadIdx.x & 63, wid = threadIdx.x >> 6;
    const int r = lane & 15, kq = lane >> 4;
    const int wm = blockIdx.y * (2 * MR * 16) + (wid >> 1) * (MR * 16);
    const int wn = blockIdx.x * (2 * NR * 16) + (wid & 1) * (NR * 16);
    const int kb = (EPI == 4) ? blockIdx.z * KT : 0;
    f32x4 acc[MR][NR] = {};
#pragma unroll 4
    for (int k0 = 0; k0 < KT; k0 += 32) {
        bf16x8 a[MR], b[NR];
#pragma unroll
        for (int i = 0; i < MR; ++i)
            a[i] = *(const bf16x8*)(A + (size_t)(wm + i * 16 + r) * lda + kb + k0 + kq * 8);
#pragma unroll
        for (int j = 0; j < NR; ++j)
            b[j] = *(const bf16x8*)(W + (size_t)(wn + j * 16 + r) * ldw + kb + k0 + kq * 8);
#pragma unroll
        for (int i = 0; i < MR; ++i)
#pragma unroll
            for (int j = 0; j < NR; ++j)
                acc[i][j] = __builtin_amdgcn_mfma_f32_16x16x32_bf16(a[i], b[j], acc[i][j], 0, 0, 0);
    }
    // C/D layout: col = lane&15, row = (lane>>4)*4 + reg
#pragma unroll
    for (int i = 0; i < MR; ++i)
#pragma unroll
        for (int j = 0; j < NR; ++j)
#pragma unroll
            for (int g = 0; g < 4; ++g) {
                const int row = wm + i * 16 + kq * 4 + g;
                const int col = wn + j * 16 + r;
                const float val = acc[i][j][g];
                if (EPI == 3) {
                    if (col < DI_) Cb1[(size_t)row * DI_ + col] = f2bs(val);
                    else Cb2[(size_t)row * DI_ + (col - DI_)] = f2bs(silu_f(val));
                } else if (EPI == 4) {
                    C[(size_t)blockIdx.z * (1024 * 512) + (size_t)row * 512 + col] = val;
                } else {
                    C[(size_t)row * N + col] = val;
                }
            }
}

// ---------------------------------------------------------------------------
// Fused conv1d+silu + xp GEMM (unchanged).
// ---------------------------------------------------------------------------
__global__ __launch_bounds__(256) void convxp_kernel(
    const unsigned short* __restrict__ xmb, const float* __restrict__ cw,
    const float* __restrict__ cb, const unsigned short* __restrict__ Wb,
    unsigned short* __restrict__ xcb, float* __restrict__ dbc)
{
    __shared__ unsigned short sA[16 * 1024];   // 32 KB, swizzled
    __shared__ float red[4][16][64];           // 16 KB
    const int tid = threadIdx.x;
    const int m0 = blockIdx.x * 16;
    // --- Phase A: conv + silu ---
    for (int task = tid; task < 16 * 128; task += 256) {
        const int rr = task >> 7;           // 0..15
        const int dd0 = (task & 127) * 8;   // 0..1016
        const int row = m0 + rr;
        const int t = row & (T_ - 1);
        float4 cw4[8];
#pragma unroll
        for (int j = 0; j < 8; ++j) cw4[j] = ((const float4*)cw)[dd0 + j];
        float acc[8];
#pragma unroll
        for (int j = 0; j < 8; ++j) acc[j] = cb[dd0 + j];
#pragma unroll
        for (int k = 0; k < DC_; ++k) {
            if (t - 3 + k >= 0) {
                const bf16x8 v = *(const bf16x8*)(xmb + (size_t)(row - 3 + k) * DI_ + dd0);
#pragma unroll
                for (int j = 0; j < 8; ++j) {
                    const float wk = (k == 0) ? cw4[j].x : (k == 1) ? cw4[j].y
                                   : (k == 2) ? cw4[j].z : cw4[j].w;
                    acc[j] += wk * bs2f((unsigned short)v[j]);
                }
            }
        }
        bf16x8 ov;
#pragma unroll
        for (int j = 0; j < 8; ++j) ov[j] = (short)f2bs(silu_f(acc[j]));
        *(bf16x8*)(xcb + (size_t)row * DI_ + dd0) = ov;
        const int byteoff = (rr * 2048 + dd0 * 2) ^ ((rr & 7) << 4);
        *(bf16x8*)((char*)sA + byteoff) = ov;
    }
    __syncthreads();
    // --- Phase B: xp GEMM, 4-way split-K over waves ---
    const int wid = tid >> 6, lane = tid & 63;
    const int r = lane & 15, kq = lane >> 4;
    f32x4 acc4[4] = {};
    const int k00 = wid * 256;
#pragma unroll
    for (int ks = 0; ks < 8; ++ks) {
        const int k0 = k00 + ks * 32;
        const int abyte = (r * 2048 + (k0 + kq * 8) * 2) ^ ((r & 7) << 4);
        const bf16x8 a = *(const bf16x8*)((const char*)sA + abyte);
#pragma unroll
        for (int j = 0; j < 4; ++j) {
            const bf16x8 bfr = *(const bf16x8*)(Wb + (size_t)(j * 16 + r) * DI_ + k0 + kq * 8);
            acc4[j] = __builtin_amdgcn_mfma_f32_16x16x32_bf16(a, bfr, acc4[j], 0, 0, 0);
        }
    }
#pragma unroll
    for (int j = 0; j < 4; ++j)
#pragma unroll
        for (int g = 0; g < 4; ++g)
            red[wid][kq * 4 + g][j * 16 + r] = acc4[j][g];
    __syncthreads();
    for (int i = tid; i < 1024; i += 256) {
        const int row = i >> 6, col = i & 63;
        const float s = red[0][row][col] + red[1][row][col] +
                        red[2][row][col] + red[3][row][col];
        dbc[(size_t)(m0 + row) * 64 + col] = s;
    }
}

// ---------------------------------------------------------------------------
// Fused selective scan, d-PER-LANE layout (R5 lesson: n-per-lane made every
// u/z access a 2B broadcast load strided 2KB -> 4x overfetch, and y a 2B
// isolated store -> 8x write-amplification).
// Block = (b, 16-wide d-tile). 256 thr = 16 chunks x 16 lanes (lane = d).
// Per-thread state: h[16](n), delta[16](t), Av[16](n) - all static-indexed.
// Pass 0: delta[t] = softplus(dbc[row,0:32] . dtw[d] + bias)  (rows L1-bcast)
// Sweep 1: local chunk scan (h0=0) -> h[16]; P[n] = exp(Av[n]*sum delta).
// Combine: LDS [chunk][d][n], thread (d,n) sequential over 16 chunks.
// Sweep 2: re-scan from h_in; y = sum_n h C + u Dp (in-thread), gate, store.
// u/z loads and y stores: 16 lanes x 2B = 32B contiguous per group. All
// loops fully unrolled: no runtime-indexed arrays (no scratch).
// ---------------------------------------------------------------------------
__global__ __launch_bounds__(256) void scan_kernel(
    const unsigned short* __restrict__ xcb, const float* __restrict__ dbc,
    const float* __restrict__ dtw, const float* __restrict__ dtbias,
    const float* __restrict__ A_log, const float* __restrict__ Dp,
    const unsigned short* __restrict__ zs, unsigned short* __restrict__ ygb)
{
    const int tid = threadIdx.x;
    const int dl = tid & 15;            // d within tile
    const int c = tid >> 4;             // chunk 0..15
    const int b = blockIdx.x >> 6;
    const int d = (blockIdx.x & 63) * 16 + dl;
    const int row0 = b * T_ + c * TC2_;
    // --- Pass 0: delta[16] ---
    float delta[TC2_];
    {
        const float4* Wp = (const float4*)(dtw + (size_t)d * R_);
        float4 w4[8];
#pragma unroll
        for (int q = 0; q < 8; ++q) w4[q] = Wp[q];
        const float bias = dtbias[d];
#pragma unroll
        for (int t = 0; t < TC2_; ++t) {
            const float4* Ap = (const float4*)(dbc + (size_t)(row0 + t) * 64);
            float acc = bias;
#pragma unroll
            for (int q = 0; q < 8; ++q) {
                const float4 a4 = Ap[q];
                acc += a4.x * w4[q].x + a4.y * w4[q].y + a4.z * w4[q].z + a4.w * w4[q].w;
            }
            delta[t] = softplus_f(acc);
        }
    }
    // --- Av[16] = -exp(A_log[d, n]) ---
    float Av[N_];
    {
        const float4* Alp = (const float4*)(A_log + (size_t)d * N_);
#pragma unroll
        for (int q = 0; q < 4; ++q) {
            const float4 v = Alp[q];
            Av[q * 4 + 0] = -__expf(v.x);
            Av[q * 4 + 1] = -__expf(v.y);
            Av[q * 4 + 2] = -__expf(v.z);
            Av[q * 4 + 3] = -__expf(v.w);
        }
    }
    const float Dd = Dp[d];
    const unsigned short* up = xcb + (size_t)row0 * DI_ + d;
    const float* bc = dbc + (size_t)row0 * 64;
    // --- Sweep 1: local chunk scan ---
    float h[N_];
#pragma unroll
    for (int n = 0; n < N_; ++n) h[n] = 0.f;
#pragma unroll
    for (int t = 0; t < TC2_; ++t) {
        const float dt_t = delta[t];
        const float dbu = dt_t * bs2f(up[t * DI_]);
        float Bv[N_];
#pragma unroll
        for (int q = 0; q < 4; ++q) {
            const float4 b4 = *(const float4*)(bc + t * 64 + R_ + q * 4);
            Bv[q * 4 + 0] = b4.x; Bv[q * 4 + 1] = b4.y;
            Bv[q * 4 + 2] = b4.z; Bv[q * 4 + 3] = b4.w;
        }
#pragma unroll
        for (int n = 0; n < N_; ++n)
            h[n] = __expf(dt_t * Av[n]) * h[n] + dbu * Bv[n];
    }
    float dsum = 0.f;
#pragma unroll
    for (int t = 0; t < TC2_; ++t) dsum += delta[t];
    // --- chunk combine via LDS ---
    __shared__ float Sl[CH2_][16][17];
    __shared__ float Pl[CH2_][16][17];
#pragma unroll
    for (int n = 0; n < N_; ++n) {
        Sl[c][dl][n] = h[n];
        Pl[c][dl][n] = __expf(Av[n] * dsum);
    }
    __syncthreads();
    {
        const int dd = tid >> 4, nn = tid & 15;
        float hin = 0.f;
#pragma unroll
        for (int c2 = 0; c2 < CH2_; ++c2) {
            const float t2 = Pl[c2][dd][nn] * hin + Sl[c2][dd][nn];
            Sl[c2][dd][nn] = hin;
            hin = t2;
        }
    }
    __syncthreads();
#pragma unroll
    for (int n = 0; n < N_; ++n) h[n] = Sl[c][dl][n];
    // --- Sweep 2: re-scan from h_in, emit gated y ---
    const unsigned short* zp = zs + (size_t)row0 * DI_ + d;
    unsigned short* yp = ygb + (size_t)row0 * DI_ + d;
#pragma unroll
    for (int t = 0; t < TC2_; ++t) {
        const float dt_t = delta[t];
        const float ut = bs2f(up[t * DI_]);
        const float dbu = dt_t * ut;
        float Bv[N_], Cv[N_];
#pragma unroll
        for (int q = 0; q < 4; ++q) {
            const float4 b4 = *(const float4*)(bc + t * 64 + R_ + q * 4);
            const float4 c4 = *(const float4*)(bc + t * 64 + R_ + N_ + q * 4);
            Bv[q * 4 + 0] = b4.x; Bv[q * 4 + 1] = b4.y;
            Bv[q * 4 + 2] = b4.z; Bv[q * 4 + 3] = b4.w;
            Cv[q * 4 + 0] = c4.x; Cv[q * 4 + 1] = c4.y;
            Cv[q * 4 + 2] = c4.z; Cv[q * 4 + 3] = c4.w;
        }
        float y = ut * Dd;
#pragma unroll
        for (int n = 0; n < N_; ++n) {
            h[n] = __expf(dt_t * Av[n]) * h[n] + dbu * Bv[n];
            y += h[n] * Cv[n];
        }
        yp[t * DI_] = f2bs(y * bs2f(zp[t * DI_]));
    }
}

// ---------------------------------------------------------------------------
// Heads
// ---------------------------------------------------------------------------
__global__ __launch_bounds__(256) void heads_kernel(
    const float* __restrict__ xn,
    const float* __restrict__ ps_w, const float* __restrict__ ps_b,
    const float* __restrict__ pa_w, const float* __restrict__ pa_b,
    float* __restrict__ out)
{
    const int idx = blockIdx.x * 4 + (threadIdx.x >> 6);
    const int lane = threadIdx.x & 63;
    const int bl = idx / 23, j = idx % 23;
    const float* tok;
    const float* wrow;
    float bias;
    float* dst;
    if (j < SD_) {
        tok = xn + ((size_t)bl * 4 + 3) * D_;
        wrow = ps_w + (size_t)j * D_;
        bias = ps_b[j];
        dst = out + (size_t)bl * SD_ + j;
    } else {
        const int jj = j - SD_;
        tok = xn + ((size_t)bl * 4 + 2) * D_;
        wrow = pa_w + (size_t)jj * D_;
        bias = pa_b[jj];
        dst = out + (size_t)B_ * L_ * SD_ + (size_t)bl * AD_ + jj;
    }
    float s = 0.f;
    for (int dd = lane; dd < D_; dd += 64) s += tok[dd] * wrow[dd];
#pragma unroll
    for (int off = 1; off < 64; off <<= 1) s += __shfl_xor(s, off);
    if (lane == 0) *dst = s + bias;
}

// ---------------------------------------------------------------------------
extern "C" void kernel_launch(void* const* d_in, const int* in_sizes, int n_in,
                              void* d_out, int out_size, void* d_ws, size_t ws_size,
                              hipStream_t stream)
{
    const float* states  = (const float*)d_in[0];
    const float* actions = (const float*)d_in[1];
    const float* rtg     = (const float*)d_in[2];
    const float* ctg     = (const float*)d_in[3];
    const int*   ts      = (const int*)d_in[4];
    const float* es_w = (const float*)d_in[5];  const float* es_b = (const float*)d_in[6];
    const float* ea_w = (const float*)d_in[7];  const float* ea_b = (const float*)d_in[8];
    const float* er_w = (const float*)d_in[9];  const float* er_b = (const float*)d_in[10];
    const float* ec_w = (const float*)d_in[11]; const float* ec_b = (const float*)d_in[12];
    const float* et_w = (const float*)d_in[13];
    const float* ln_w = (const float*)d_in[14]; const float* ln_b = (const float*)d_in[15];
    const float* in_w = (const float*)d_in[16];
    const float* conv_w = (const float*)d_in[17]; const float* conv_b = (const float*)d_in[18];
    const float* xp_w = (const float*)d_in[19];
    const float* dtp_w = (const float*)d_in[20]; const float* dtp_b = (const float*)d_in[21];
    const float* A_log = (const float*)d_in[22]; const float* Dp = (const float*)d_in[23];
    const float* out_w = (const float*)d_in[24];
    const float* fn_w = (const float*)d_in[25]; const float* fn_b = (const float*)d_in[26];
    const float* ps_w = (const float*)d_in[27]; const float* ps_b = (const float*)d_in[28];
    const float* pa_w = (const float*)d_in[29]; const float* pa_b = (const float*)d_in[30];
    float* out = (float*)d_out;

    // workspace layout
    float* ws   = (float*)d_ws;
    float* x    = ws;                    // 524288 f32
    float* xn   = x + 524288;            // 524288 f32 (final LN out)
    float* p    = xn + 524288;           // 1048576 f32 (out_proj partials p0|p1)
    float* dbc  = p + 1048576;           // 65536 f32
    unsigned short* xnb = (unsigned short*)(dbc + 65536);  // 524288 bf16
    unsigned short* xmb = xnb + 524288;                    // 1048576 bf16
    unsigned short* xcb = xmb + 1048576;                   // 1048576 bf16
    unsigned short* zs  = xcb + 1048576;                   // 1048576 bf16
    unsigned short* ygb = zs + 1048576;                    // 1048576 bf16
    unsigned short* wb  = ygb + 1048576;                   // 6553600 bf16
    unsigned short* wb_in  = wb;
    unsigned short* wb_out = wb + NW_IN;
    unsigned short* wb_xp  = wb + NW_IN + NW_OUT;

    wcvt_kernel<<<(NW_TOT / 4 + 255) / 256, 256, 0, stream>>>(in_w, out_w, xp_w, wb);
    embed_kernel<<<B_ * L_, D_, 0, stream>>>(states, actions, rtg, ctg, ts,
        es_w, es_b, ea_w, ea_b, er_w, er_b, ec_w, ec_b, et_w, x);

    for (int i = 0; i < NL_; ++i) {
        if (i == 0)
            ln2_kernel<0><<<B_ * T_, 256, 0, stream>>>(
                x, nullptr, nullptr, ln_w, ln_b, xnb);
        else
            ln2_kernel<1><<<B_ * T_, 256, 0, stream>>>(
                x, p, p + 524288, ln_w + i * D_, ln_b + i * D_, xnb);
        // in_proj: (1024 x 2048 x 512) -> xmb bf16 | zs=silu(z) bf16
        gemm3<2, 2, 3, 512><<<dim3(32, 16), 256, 0, stream>>>(
            xnb, D_, wb_in + (size_t)i * 2 * DI_ * D_, D_, nullptr, xmb, zs, 2 * DI_);
        // conv+silu fused with xp GEMM -> xcb bf16, dbc fp32
        convxp_kernel<<<64, 256, 0, stream>>>(
            xmb, conv_w + i * DI_ * DC_, conv_b + i * DI_,
            wb_xp + (size_t)i * 64 * DI_, xcb, dbc);
        // fused delta + chunked scan + gate -> ygb bf16
        scan_kernel<<<B_ * (DI_ / 16), 256, 0, stream>>>(
            xcb, dbc, dtp_w + (size_t)i * DI_ * R_, dtp_b + i * DI_,
            A_log + (size_t)i * DI_ * N_, Dp + i * DI_, zs, ygb);
        // out_proj split-K=2: p[z] = yg[:, z*512:+512] @ W[:, z*512:+512]^T
        gemm3<2, 2, 4, 512><<<dim3(8, 16, 2), 256, 0, stream>>>(
            ygb, DI_, wb_out + (size_t)i * D_ * DI_, DI_, p, nullptr, nullptr, D_);
    }

    ln2_kernel<2><<<B_ * T_, 256, 0, stream>>>(x, p, p + 524288, fn_w, fn_b, xn);
    heads_kernel<<<(B_ * L_ * 23) / 4, 256, 0, stream>>>(xn, ps_w, ps_b, pa_w, pa_b, out);
}

// Round 7
// 368.379 us; speedup vs baseline: 1.5498x; 1.2378x over previous
//
#include <hip/hip_runtime.h>
#include <math.h>

#define B_ 4
#define L_ 64
#define D_ 512
#define DI_ 1024
#define N_ 16
#define DC_ 4
#define R_ 32
#define NL_ 4
#define SD_ 17
#define AD_ 6
#define T_ 256    // 4*L
#define CH2_ 16   // scan chunks (d-per-lane layout)
#define TC2_ 16   // T_/CH2_

// bf16 weight segment sizes (elements)
#define NW_IN  (NL_ * 2 * DI_ * D_)   // 4194304
#define NW_OUT (NL_ * D_ * DI_)       // 2097152
#define NW_XP  (NL_ * 64 * DI_)       // 262144
#define NW_TOT (NW_IN + NW_OUT + NW_XP)  // 6553600

typedef short bf16x8 __attribute__((ext_vector_type(8)));
typedef float f32x4 __attribute__((ext_vector_type(4)));

__device__ __forceinline__ float silu_f(float v) { return v / (1.f + __expf(-v)); }
__device__ __forceinline__ float softplus_f(float v) {
    return fmaxf(v, 0.f) + log1pf(__expf(-fabsf(v)));
}
__device__ __forceinline__ unsigned short f2bs(float f) {
    unsigned u = __float_as_uint(f);
    u += 0x7fffu + ((u >> 16) & 1u);
    return (unsigned short)(u >> 16);
}
__device__ __forceinline__ float bs2f(unsigned short s) {
    return __uint_as_float(((unsigned)s) << 16);
}

// ---------------------------------------------------------------------------
// One-time: weights fp32 -> bf16 (in_w | out_w | xp_w)
// ---------------------------------------------------------------------------
__global__ __launch_bounds__(256) void wcvt_kernel(
    const float* __restrict__ in_w, const float* __restrict__ out_w,
    const float* __restrict__ xp_w, unsigned short* __restrict__ wb)
{
    const int i = blockIdx.x * 256 + threadIdx.x;   // float4 index
    if (i >= NW_TOT / 4) return;
    const int e = i * 4;
    const float* src; int off;
    if (e < NW_IN)               { src = in_w;  off = e; }
    else if (e < NW_IN + NW_OUT) { src = out_w; off = e - NW_IN; }
    else                         { src = xp_w;  off = e - NW_IN - NW_OUT; }
    const float4 v = *(const float4*)(src + off);
    ushort4 o;
    o.x = f2bs(v.x); o.y = f2bs(v.y); o.z = f2bs(v.z); o.w = f2bs(v.w);
    *(ushort4*)(wb + e) = o;
}

// ---------------------------------------------------------------------------
// Embedding
// ---------------------------------------------------------------------------
__global__ __launch_bounds__(512) void embed_kernel(
    const float* __restrict__ states, const float* __restrict__ actions,
    const float* __restrict__ rtg, const float* __restrict__ ctg,
    const int* __restrict__ ts,
    const float* __restrict__ es_w, const float* __restrict__ es_b,
    const float* __restrict__ ea_w, const float* __restrict__ ea_b,
    const float* __restrict__ er_w, const float* __restrict__ er_b,
    const float* __restrict__ ec_w, const float* __restrict__ ec_b,
    const float* __restrict__ et_w, float* __restrict__ x)
{
    const int bl = blockIdx.x;
    const int d = threadIdx.x;
    const float te = et_w[(size_t)ts[bl] * D_ + d];
    const float r = rtg[bl] * er_w[d] + er_b[d] + te;
    const float c = ctg[bl] * ec_w[d] + ec_b[d] + te;
    float s = es_b[d] + te;
#pragma unroll
    for (int k = 0; k < SD_; ++k) s += states[bl * SD_ + k] * es_w[d * SD_ + k];
    float a = ea_b[d] + te;
#pragma unroll
    for (int k = 0; k < AD_; ++k) a += actions[bl * AD_ + k] * ea_w[d * AD_ + k];
    float* xp = x + (size_t)bl * 4 * D_;
    xp[0 * D_ + d] = r;
    xp[1 * D_ + d] = c;
    xp[2 * D_ + d] = s;
    xp[3 * D_ + d] = a;
}

// ---------------------------------------------------------------------------
// LayerNorm (+ optional residual partial sum from split-K out_proj).
// MODE 0: ln(x) -> bf16 out.  MODE 1: x += p0+p1 (stored), ln -> bf16 out.
// MODE 2: x += p0+p1, ln -> fp32 out.
// ---------------------------------------------------------------------------
template <int MODE>
__global__ __launch_bounds__(256) void ln2_kernel(
    float* __restrict__ x, const float* __restrict__ p0,
    const float* __restrict__ p1,
    const float* __restrict__ w, const float* __restrict__ b,
    void* __restrict__ o_)
{
    const int tok = blockIdx.x;
    const int tid = threadIdx.x;
    float2 v = reinterpret_cast<float2*>(x + (size_t)tok * D_)[tid];
    if (MODE >= 1) {
        const float2 a0 = reinterpret_cast<const float2*>(p0 + (size_t)tok * D_)[tid];
        const float2 a1 = reinterpret_cast<const float2*>(p1 + (size_t)tok * D_)[tid];
        v.x += a0.x + a1.x;
        v.y += a0.y + a1.y;
        reinterpret_cast<float2*>(x + (size_t)tok * D_)[tid] = v;
    }
    float s = v.x + v.y;
#pragma unroll
    for (int off = 1; off < 64; off <<= 1) s += __shfl_xor(s, off);
    __shared__ float red[8];
    const int wv = tid >> 6;
    if ((tid & 63) == 0) red[wv] = s;
    __syncthreads();
    const float mean = (red[0] + red[1] + red[2] + red[3]) * (1.f / D_);
    const float dx = v.x - mean, dy = v.y - mean;
    float q = dx * dx + dy * dy;
#pragma unroll
    for (int off = 1; off < 64; off <<= 1) q += __shfl_xor(q, off);
    if ((tid & 63) == 0) red[4 + wv] = q;
    __syncthreads();
    const float var = (red[4] + red[5] + red[6] + red[7]) * (1.f / D_);
    const float r = rsqrtf(var + 1e-5f);
    const int d0 = tid * 2;
    const float o0 = dx * r * w[d0] + b[d0];
    const float o1 = dy * r * w[d0 + 1] + b[d0 + 1];
    if (MODE == 2) {
        float* o = (float*)o_;
        o[(size_t)tok * D_ + d0] = o0;
        o[(size_t)tok * D_ + d0 + 1] = o1;
    } else {
        unsigned short* o = (unsigned short*)o_;
        o[(size_t)tok * D_ + d0] = f2bs(o0);
        o[(size_t)tok * D_ + d0 + 1] = f2bs(o1);
    }
}

// ---------------------------------------------------------------------------
// MFMA bf16 GEMM, A and W both bf16, K compile-time.
// EPI 3: in_proj split store (col<DI -> xmb bf16; col>=DI -> zs=silu bf16)
// EPI 4: split-K partial store to C + blockIdx.z*(1024*512), k base z*KT
// EPI 0: plain fp32 store
// ---------------------------------------------------------------------------
template <int MR, int NR, int EPI, int KT>
__global__ __launch_bounds__(256) void gemm3(
    const unsigned short* __restrict__ A, int lda,
    const unsigned short* __restrict__ W, int ldw,
    float* __restrict__ C, unsigned short* __restrict__ Cb1,
    unsigned short* __restrict__ Cb2, int N)
{
    const int lane = threadIdx.x & 63, wid = threadIdx.x >> 6;
    const int r = lane & 15, kq = lane >> 4;
    const int wm = blockIdx.y * (2 * MR * 16) + (wid >> 1) * (MR * 16);
    const int wn = blockIdx.x * (2 * NR * 16) + (wid & 1) * (NR * 16);
    const int kb = (EPI == 4) ? blockIdx.z * KT : 0;
    f32x4 acc[MR][NR] = {};
#pragma unroll 4
    for (int k0 = 0; k0 < KT; k0 += 32) {
        bf16x8 a[MR], b[NR];
#pragma unroll
        for (int i = 0; i < MR; ++i)
            a[i] = *(const bf16x8*)(A + (size_t)(wm + i * 16 + r) * lda + kb + k0 + kq * 8);
#pragma unroll
        for (int j = 0; j < NR; ++j)
            b[j] = *(const bf16x8*)(W + (size_t)(wn + j * 16 + r) * ldw + kb + k0 + kq * 8);
#pragma unroll
        for (int i = 0; i < MR; ++i)
#pragma unroll
            for (int j = 0; j < NR; ++j)
                acc[i][j] = __builtin_amdgcn_mfma_f32_16x16x32_bf16(a[i], b[j], acc[i][j], 0, 0, 0);
    }
    // C/D layout: col = lane&15, row = (lane>>4)*4 + reg
#pragma unroll
    for (int i = 0; i < MR; ++i)
#pragma unroll
        for (int j = 0; j < NR; ++j)
#pragma unroll
            for (int g = 0; g < 4; ++g) {
                const int row = wm + i * 16 + kq * 4 + g;
                const int col = wn + j * 16 + r;
                const float val = acc[i][j][g];
                if (EPI == 3) {
                    if (col < DI_) Cb1[(size_t)row * DI_ + col] = f2bs(val);
                    else Cb2[(size_t)row * DI_ + (col - DI_)] = f2bs(silu_f(val));
                } else if (EPI == 4) {
                    C[(size_t)blockIdx.z * (1024 * 512) + (size_t)row * 512 + col] = val;
                } else {
                    C[(size_t)row * N + col] = val;
                }
            }
}

// ---------------------------------------------------------------------------
// Fused conv1d+silu + xp GEMM (unchanged).
// ---------------------------------------------------------------------------
__global__ __launch_bounds__(256) void convxp_kernel(
    const unsigned short* __restrict__ xmb, const float* __restrict__ cw,
    const float* __restrict__ cb, const unsigned short* __restrict__ Wb,
    unsigned short* __restrict__ xcb, float* __restrict__ dbc)
{
    __shared__ unsigned short sA[16 * 1024];   // 32 KB, swizzled
    __shared__ float red[4][16][64];           // 16 KB
    const int tid = threadIdx.x;
    const int m0 = blockIdx.x * 16;
    // --- Phase A: conv + silu ---
    for (int task = tid; task < 16 * 128; task += 256) {
        const int rr = task >> 7;           // 0..15
        const int dd0 = (task & 127) * 8;   // 0..1016
        const int row = m0 + rr;
        const int t = row & (T_ - 1);
        float4 cw4[8];
#pragma unroll
        for (int j = 0; j < 8; ++j) cw4[j] = ((const float4*)cw)[dd0 + j];
        float acc[8];
#pragma unroll
        for (int j = 0; j < 8; ++j) acc[j] = cb[dd0 + j];
#pragma unroll
        for (int k = 0; k < DC_; ++k) {
            if (t - 3 + k >= 0) {
                const bf16x8 v = *(const bf16x8*)(xmb + (size_t)(row - 3 + k) * DI_ + dd0);
#pragma unroll
                for (int j = 0; j < 8; ++j) {
                    const float wk = (k == 0) ? cw4[j].x : (k == 1) ? cw4[j].y
                                   : (k == 2) ? cw4[j].z : cw4[j].w;
                    acc[j] += wk * bs2f((unsigned short)v[j]);
                }
            }
        }
        bf16x8 ov;
#pragma unroll
        for (int j = 0; j < 8; ++j) ov[j] = (short)f2bs(silu_f(acc[j]));
        *(bf16x8*)(xcb + (size_t)row * DI_ + dd0) = ov;
        const int byteoff = (rr * 2048 + dd0 * 2) ^ ((rr & 7) << 4);
        *(bf16x8*)((char*)sA + byteoff) = ov;
    }
    __syncthreads();
    // --- Phase B: xp GEMM, 4-way split-K over waves ---
    const int wid = tid >> 6, lane = tid & 63;
    const int r = lane & 15, kq = lane >> 4;
    f32x4 acc4[4] = {};
    const int k00 = wid * 256;
#pragma unroll
    for (int ks = 0; ks < 8; ++ks) {
        const int k0 = k00 + ks * 32;
        const int abyte = (r * 2048 + (k0 + kq * 8) * 2) ^ ((r & 7) << 4);
        const bf16x8 a = *(const bf16x8*)((const char*)sA + abyte);
#pragma unroll
        for (int j = 0; j < 4; ++j) {
            const bf16x8 bfr = *(const bf16x8*)(Wb + (size_t)(j * 16 + r) * DI_ + k0 + kq * 8);
            acc4[j] = __builtin_amdgcn_mfma_f32_16x16x32_bf16(a, bfr, acc4[j], 0, 0, 0);
        }
    }
#pragma unroll
    for (int j = 0; j < 4; ++j)
#pragma unroll
        for (int g = 0; g < 4; ++g)
            red[wid][kq * 4 + g][j * 16 + r] = acc4[j][g];
    __syncthreads();
    for (int i = tid; i < 1024; i += 256) {
        const int row = i >> 6, col = i & 63;
        const float s = red[0][row][col] + red[1][row][col] +
                        red[2][row][col] + red[3][row][col];
        dbc[(size_t)(m0 + row) * 64 + col] = s;
    }
}

// ---------------------------------------------------------------------------
// Fused selective scan, d-per-lane, REGISTER-LEAN (R6 lesson: delta[16] +
// Bv/Cv[16] temporaries pushed VGPR to the 256 cap -> spills -> 21 MB scratch
// writes, 9% occupancy).
// Changes: (a) delta computed in prologue into padded LDS [256][17] -- the
// w4[8] weight regs die before the scan loops; (b) B/C consumed one float4
// at a time, updating 4 h[n] immediately (no 16-float temporaries).
// Live state in scan loops: h[16] + Av[16] + ~15 misc ~= 55 VGPR.
// __launch_bounds__(256,4) caps allocation at 128 VGPR (>=4 waves/SIMD).
// ---------------------------------------------------------------------------
__global__ __launch_bounds__(256, 4) void scan_kernel(
    const unsigned short* __restrict__ xcb, const float* __restrict__ dbc,
    const float* __restrict__ dtw, const float* __restrict__ dtbias,
    const float* __restrict__ A_log, const float* __restrict__ Dp,
    const unsigned short* __restrict__ zs, unsigned short* __restrict__ ygb)
{
    __shared__ float dlt_s[T_][17];     // 17.4 KB, padded (bank spread)
    __shared__ float Sl[CH2_][16][17];  // 17.4 KB
    __shared__ float Pl[CH2_][16][17];  // 17.4 KB
    const int tid = threadIdx.x;
    const int dl = tid & 15;            // d within 16-wide tile
    const int c = tid >> 4;             // chunk 0..15
    const int b = blockIdx.x >> 6;
    const int d = (blockIdx.x & 63) * 16 + dl;
    const int row0 = b * T_ + c * TC2_;
    // --- prologue: delta -> LDS (w4 regs die here) ---
    {
        const float4* Wp = (const float4*)(dtw + (size_t)d * R_);
        float4 w4[8];
#pragma unroll
        for (int q = 0; q < 8; ++q) w4[q] = Wp[q];
        const float bias = dtbias[d];
#pragma unroll
        for (int t = 0; t < TC2_; ++t) {
            const float4* Ap = (const float4*)(dbc + (size_t)(row0 + t) * 64);
            float acc = bias;
#pragma unroll
            for (int q = 0; q < 8; ++q) {
                const float4 a4 = Ap[q];
                acc += a4.x * w4[q].x + a4.y * w4[q].y + a4.z * w4[q].z + a4.w * w4[q].w;
            }
            dlt_s[c * TC2_ + t][dl] = softplus_f(acc);
        }
    }
    // --- Av[16] = -exp(A_log[d, n]) ---
    float Av[N_];
    {
        const float4* Alp = (const float4*)(A_log + (size_t)d * N_);
#pragma unroll
        for (int q = 0; q < 4; ++q) {
            const float4 v = Alp[q];
            Av[q * 4 + 0] = -__expf(v.x);
            Av[q * 4 + 1] = -__expf(v.y);
            Av[q * 4 + 2] = -__expf(v.z);
            Av[q * 4 + 3] = -__expf(v.w);
        }
    }
    __syncthreads();
    const unsigned short* up = xcb + (size_t)row0 * DI_ + d;
    const float* bc = dbc + (size_t)row0 * 64;
    // --- Sweep 1: local chunk scan ---
    float h[N_];
#pragma unroll
    for (int n = 0; n < N_; ++n) h[n] = 0.f;
    float dsum = 0.f;
#pragma unroll
    for (int t = 0; t < TC2_; ++t) {
        const float dt_t = dlt_s[c * TC2_ + t][dl];
        dsum += dt_t;
        const float dbu = dt_t * bs2f(up[t * DI_]);
#pragma unroll
        for (int q = 0; q < 4; ++q) {
            const float4 b4 = *(const float4*)(bc + t * 64 + R_ + q * 4);
            h[q * 4 + 0] = __expf(dt_t * Av[q * 4 + 0]) * h[q * 4 + 0] + dbu * b4.x;
            h[q * 4 + 1] = __expf(dt_t * Av[q * 4 + 1]) * h[q * 4 + 1] + dbu * b4.y;
            h[q * 4 + 2] = __expf(dt_t * Av[q * 4 + 2]) * h[q * 4 + 2] + dbu * b4.z;
            h[q * 4 + 3] = __expf(dt_t * Av[q * 4 + 3]) * h[q * 4 + 3] + dbu * b4.w;
        }
    }
    // --- chunk combine via LDS ---
#pragma unroll
    for (int n = 0; n < N_; ++n) {
        Sl[c][dl][n] = h[n];
        Pl[c][dl][n] = __expf(Av[n] * dsum);
    }
    __syncthreads();
    {
        const int dd = tid >> 4, nn = tid & 15;
        float hin = 0.f;
#pragma unroll
        for (int c2 = 0; c2 < CH2_; ++c2) {
            const float t2 = Pl[c2][dd][nn] * hin + Sl[c2][dd][nn];
            Sl[c2][dd][nn] = hin;
            hin = t2;
        }
    }
    __syncthreads();
#pragma unroll
    for (int n = 0; n < N_; ++n) h[n] = Sl[c][dl][n];
    // --- Sweep 2: re-scan from h_in, emit gated y ---
    const float Dd = Dp[d];
    const unsigned short* zp = zs + (size_t)row0 * DI_ + d;
    unsigned short* yp = ygb + (size_t)row0 * DI_ + d;
#pragma unroll
    for (int t = 0; t < TC2_; ++t) {
        const float dt_t = dlt_s[c * TC2_ + t][dl];
        const float ut = bs2f(up[t * DI_]);
        const float dbu = dt_t * ut;
        float y = ut * Dd;
#pragma unroll
        for (int q = 0; q < 4; ++q) {
            const float4 b4 = *(const float4*)(bc + t * 64 + R_ + q * 4);
            const float4 c4 = *(const float4*)(bc + t * 64 + R_ + N_ + q * 4);
            h[q * 4 + 0] = __expf(dt_t * Av[q * 4 + 0]) * h[q * 4 + 0] + dbu * b4.x;
            h[q * 4 + 1] = __expf(dt_t * Av[q * 4 + 1]) * h[q * 4 + 1] + dbu * b4.y;
            h[q * 4 + 2] = __expf(dt_t * Av[q * 4 + 2]) * h[q * 4 + 2] + dbu * b4.z;
            h[q * 4 + 3] = __expf(dt_t * Av[q * 4 + 3]) * h[q * 4 + 3] + dbu * b4.w;
            y += h[q * 4 + 0] * c4.x + h[q * 4 + 1] * c4.y
               + h[q * 4 + 2] * c4.z + h[q * 4 + 3] * c4.w;
        }
        yp[t * DI_] = f2bs(y * bs2f(zp[t * DI_]));
    }
}

// ---------------------------------------------------------------------------
// Heads
// ---------------------------------------------------------------------------
__global__ __launch_bounds__(256) void heads_kernel(
    const float* __restrict__ xn,
    const float* __restrict__ ps_w, const float* __restrict__ ps_b,
    const float* __restrict__ pa_w, const float* __restrict__ pa_b,
    float* __restrict__ out)
{
    const int idx = blockIdx.x * 4 + (threadIdx.x >> 6);
    const int lane = threadIdx.x & 63;
    const int bl = idx / 23, j = idx % 23;
    const float* tok;
    const float* wrow;
    float bias;
    float* dst;
    if (j < SD_) {
        tok = xn + ((size_t)bl * 4 + 3) * D_;
        wrow = ps_w + (size_t)j * D_;
        bias = ps_b[j];
        dst = out + (size_t)bl * SD_ + j;
    } else {
        const int jj = j - SD_;
        tok = xn + ((size_t)bl * 4 + 2) * D_;
        wrow = pa_w + (size_t)jj * D_;
        bias = pa_b[jj];
        dst = out + (size_t)B_ * L_ * SD_ + (size_t)bl * AD_ + jj;
    }
    float s = 0.f;
    for (int dd = lane; dd < D_; dd += 64) s += tok[dd] * wrow[dd];
#pragma unroll
    for (int off = 1; off < 64; off <<= 1) s += __shfl_xor(s, off);
    if (lane == 0) *dst = s + bias;
}

// ---------------------------------------------------------------------------
extern "C" void kernel_launch(void* const* d_in, const int* in_sizes, int n_in,
                              void* d_out, int out_size, void* d_ws, size_t ws_size,
                              hipStream_t stream)
{
    const float* states  = (const float*)d_in[0];
    const float* actions = (const float*)d_in[1];
    const float* rtg     = (const float*)d_in[2];
    const float* ctg     = (const float*)d_in[3];
    const int*   ts      = (const int*)d_in[4];
    const float* es_w = (const float*)d_in[5];  const float* es_b = (const float*)d_in[6];
    const float* ea_w = (const float*)d_in[7];  const float* ea_b = (const float*)d_in[8];
    const float* er_w = (const float*)d_in[9];  const float* er_b = (const float*)d_in[10];
    const float* ec_w = (const float*)d_in[11]; const float* ec_b = (const float*)d_in[12];
    const float* et_w = (const float*)d_in[13];
    const float* ln_w = (const float*)d_in[14]; const float* ln_b = (const float*)d_in[15];
    const float* in_w = (const float*)d_in[16];
    const float* conv_w = (const float*)d_in[17]; const float* conv_b = (const float*)d_in[18];
    const float* xp_w = (const float*)d_in[19];
    const float* dtp_w = (const float*)d_in[20]; const float* dtp_b = (const float*)d_in[21];
    const float* A_log = (const float*)d_in[22]; const float* Dp = (const float*)d_in[23];
    const float* out_w = (const float*)d_in[24];
    const float* fn_w = (const float*)d_in[25]; const float* fn_b = (const float*)d_in[26];
    const float* ps_w = (const float*)d_in[27]; const float* ps_b = (const float*)d_in[28];
    const float* pa_w = (const float*)d_in[29]; const float* pa_b = (const float*)d_in[30];
    float* out = (float*)d_out;

    // workspace layout
    float* ws   = (float*)d_ws;
    float* x    = ws;                    // 524288 f32
    float* xn   = x + 524288;            // 524288 f32 (final LN out)
    float* p    = xn + 524288;           // 1048576 f32 (out_proj partials p0|p1)
    float* dbc  = p + 1048576;           // 65536 f32
    unsigned short* xnb = (unsigned short*)(dbc + 65536);  // 524288 bf16
    unsigned short* xmb = xnb + 524288;                    // 1048576 bf16
    unsigned short* xcb = xmb + 1048576;                   // 1048576 bf16
    unsigned short* zs  = xcb + 1048576;                   // 1048576 bf16
    unsigned short* ygb = zs + 1048576;                    // 1048576 bf16
    unsigned short* wb  = ygb + 1048576;                   // 6553600 bf16
    unsigned short* wb_in  = wb;
    unsigned short* wb_out = wb + NW_IN;
    unsigned short* wb_xp  = wb + NW_IN + NW_OUT;

    wcvt_kernel<<<(NW_TOT / 4 + 255) / 256, 256, 0, stream>>>(in_w, out_w, xp_w, wb);
    embed_kernel<<<B_ * L_, D_, 0, stream>>>(states, actions, rtg, ctg, ts,
        es_w, es_b, ea_w, ea_b, er_w, er_b, ec_w, ec_b, et_w, x);

    for (int i = 0; i < NL_; ++i) {
        if (i == 0)
            ln2_kernel<0><<<B_ * T_, 256, 0, stream>>>(
                x, nullptr, nullptr, ln_w, ln_b, xnb);
        else
            ln2_kernel<1><<<B_ * T_, 256, 0, stream>>>(
                x, p, p + 524288, ln_w + i * D_, ln_b + i * D_, xnb);
        // in_proj: (1024 x 2048 x 512) -> xmb bf16 | zs=silu(z) bf16
        gemm3<2, 2, 3, 512><<<dim3(32, 16), 256, 0, stream>>>(
            xnb, D_, wb_in + (size_t)i * 2 * DI_ * D_, D_, nullptr, xmb, zs, 2 * DI_);
        // conv+silu fused with xp GEMM -> xcb bf16, dbc fp32
        convxp_kernel<<<64, 256, 0, stream>>>(
            xmb, conv_w + i * DI_ * DC_, conv_b + i * DI_,
            wb_xp + (size_t)i * 64 * DI_, xcb, dbc);
        // fused delta + chunked scan + gate -> ygb bf16
        scan_kernel<<<B_ * (DI_ / 16), 256, 0, stream>>>(
            xcb, dbc, dtp_w + (size_t)i * DI_ * R_, dtp_b + i * DI_,
            A_log + (size_t)i * DI_ * N_, Dp + i * DI_, zs, ygb);
        // out_proj split-K=2: p[z] = yg[:, z*512:+512] @ W[:, z*512:+512]^T
        gemm3<2, 2, 4, 512><<<dim3(8, 16, 2), 256, 0, stream>>>(
            ygb, DI_, wb_out + (size_t)i * D_ * DI_, DI_, p, nullptr, nullptr, D_);
    }

    ln2_kernel<2><<<B_ * T_, 256, 0, stream>>>(x, p, p + 524288, fn_w, fn_b, xn);
    heads_kernel<<<(B_ * L_ * 23) / 4, 256, 0, stream>>>(xn, ps_w, ps_b, pa_w, pa_b, out);
}